// Round 3
// baseline (589.256 us; speedup 1.0000x reference)
//
#include <hip/hip_runtime.h>

typedef unsigned short u16;
typedef unsigned int   u32;
typedef unsigned long long u64;
typedef __bf16 bf16x8 __attribute__((ext_vector_type(8)));
typedef float  f32x4  __attribute__((ext_vector_type(4)));
typedef float  f32x16 __attribute__((ext_vector_type(16)));

__device__ __forceinline__ u16 f2bf(float f) {
    u32 u = __float_as_uint(f);
    return (u16)((u + 0x7FFFu + ((u >> 16) & 1u)) >> 16);
}
__device__ __forceinline__ float elu(float x) { return x > 0.f ? x : expm1f(x); }

__device__ __forceinline__ void gload_lds16(const void* g, void* l) {
    __builtin_amdgcn_global_load_lds(
        (const __attribute__((address_space(1))) void*)g,
        (__attribute__((address_space(3))) void*)l, 16, 0, 0);
}

__device__ __forceinline__ u32 cvtpk(float a, float b) {
    u32 r;
    asm("v_cvt_pk_bf16_f32 %0, %1, %2" : "=v"(r) : "v"(a), "v"(b));
    return r;
}
__device__ __forceinline__ void plswap(u32& a, u32& b) {
    asm volatile("v_permlane32_swap_b32 %0, %1" : "+v"(a), "+v"(b));
}

// ---------------- weight transpose + fp32->bf16 : Wt[j][k] = bf16(W[k][j]) ----
__global__ __launch_bounds__(256) void transpose_w(const float* __restrict__ W,
                                                   u16* __restrict__ Wt) {
    __shared__ float t[32][33];
    int j0 = blockIdx.x * 32, k0 = blockIdx.y * 32;
    int tx = threadIdx.x, ty = threadIdx.y; // 32 x 8
#pragma unroll
    for (int i = 0; i < 4; ++i)
        t[ty + i * 8][tx] = W[(long)(k0 + ty + i * 8) * 1024 + j0 + tx];
    __syncthreads();
#pragma unroll
    for (int i = 0; i < 4; ++i)
        Wt[(long)(j0 + ty + i * 8) * 1024 + k0 + tx] = f2bf(t[tx][ty + i * 8]);
}

// ---------------- fp32 -> bf16 bulk convert ---------------------------------
__global__ __launch_bounds__(256) void cvt_bf16(const float* __restrict__ X,
                                                u16* __restrict__ Y, int n4) {
    int i = blockIdx.x * 256 + threadIdx.x;
    int st = gridDim.x * 256;
    for (; i < n4; i += st) {
        float4 v = ((const float4*)X)[i];
        u64 pk = (u64)f2bf(v.x) | ((u64)f2bf(v.y) << 16) |
                 ((u64)f2bf(v.z) << 32) | ((u64)f2bf(v.w) << 48);
        ((u64*)Y)[i] = pk;
    }
}

// ---------------- mask int32 -> bitmask (bit=1 means masked out) -------------
__global__ __launch_bounds__(256) void pack_mask(const int* __restrict__ mask,
                                                 u64* __restrict__ bits, long n64) {
    long wid  = ((long)blockIdx.x * blockDim.x + threadIdx.x) >> 6;
    int  lane = threadIdx.x & 63;
    long nw   = ((long)gridDim.x * blockDim.x) >> 6;
    for (long w = wid; w < n64; w += nw) {
        int m = mask[w * 64 + lane];
        u64 b = __ballot(m != 0);
        if (lane == 0) bits[w] = b;
    }
}

// ---------------- GEMM: C = EPI(elu(A @ Bt^T + bias)) -----------------------
// A: bf16 [8192][1024], Bt: bf16 [N][K] (pre-transposed)
// EPI: 0=Q (bf16, *0.125*log2e), 1=K (bf16), 2=V -> Vt[b,h,d,s] bf16, 3=out fp32
template <int EPI>
__global__ __launch_bounds__(256) void gemm_epi(const u16* __restrict__ A,
                                                const u16* __restrict__ Bt,
                                                const float* __restrict__ bias,
                                                void* __restrict__ Cout) {
    constexpr int K = 1024;
    __shared__ u16 As[128][32];
    __shared__ u16 Bs[128][32];
    const int tid = threadIdx.x;
    const int lane = tid & 63, w = tid >> 6;
    const int wm = w >> 1, wn = w & 1;
    // XCD-aware swizzle: 512 blocks = 8 XCDs x 64; each XCD owns one N-panel
    const int vb = ((blockIdx.x & 7) << 6) + (blockIdx.x >> 3);
    const int m0 = (vb & 63) * 128;
    const int n0 = (vb >> 6) * 128;
    const int lrow = lane & 15;
    const int kc = (lane >> 4) * 8;

    f32x4 acc[4][4] = {};

    for (int k0 = 0; k0 < K; k0 += 32) {
        {
            const u16* g0 = A + (long)(m0 + w * 16 + (lane >> 2)) * K + k0 + (lane & 3) * 8;
            gload_lds16(g0, (char*)As + w * 1024);
            gload_lds16(g0 + 64 * K, (char*)As + 4096 + w * 1024);
        }
        {
            const u16* g0 = Bt + (long)(n0 + w * 16 + (lane >> 2)) * K + k0 + (lane & 3) * 8;
            gload_lds16(g0, (char*)Bs + w * 1024);
            gload_lds16(g0 + 64 * K, (char*)Bs + 4096 + w * 1024);
        }
        __syncthreads();
        bf16x8 af[4], bfr[4];
#pragma unroll
        for (int mi = 0; mi < 4; ++mi)
            af[mi] = *(const bf16x8*)&As[wm * 64 + mi * 16 + lrow][kc];
#pragma unroll
        for (int ni = 0; ni < 4; ++ni)
            bfr[ni] = *(const bf16x8*)&Bs[wn * 64 + ni * 16 + lrow][kc];
#pragma unroll
        for (int mi = 0; mi < 4; ++mi)
#pragma unroll
            for (int ni = 0; ni < 4; ++ni)
                acc[mi][ni] = __builtin_amdgcn_mfma_f32_16x16x32_bf16(
                    af[mi], bfr[ni], acc[mi][ni], 0, 0, 0);
        __syncthreads();
    }

    const int rbase = m0 + wm * 64 + (lane >> 4) * 4;
    const int cbase = n0 + wn * 64 + lrow;
#pragma unroll
    for (int mi = 0; mi < 4; ++mi)
#pragma unroll
        for (int ni = 0; ni < 4; ++ni) {
            int row = rbase + mi * 16;
            int col = cbase + ni * 16;
            float bsv = bias[col];
            f32x4 a = acc[mi][ni];
            if (EPI == 0 || EPI == 1) {
                u16* O = (u16*)Cout;
#pragma unroll
                for (int r = 0; r < 4; ++r) {
                    float v = elu(a[r] + bsv);
                    if (EPI == 0) v *= 0.18033688011112042f; // (1/8)*log2(e)
                    O[(long)(row + r) * 1024 + col] = f2bf(v);
                }
            } else if (EPI == 2) {
                u16* O = (u16*)Cout;
                int bb = row >> 11, s = row & 2047;
                int hh = col >> 6, d = col & 63;
                u64 pk = (u64)f2bf(elu(a[0] + bsv)) |
                         ((u64)f2bf(elu(a[1] + bsv)) << 16) |
                         ((u64)f2bf(elu(a[2] + bsv)) << 32) |
                         ((u64)f2bf(elu(a[3] + bsv)) << 48);
                *(u64*)&O[((long)(bb * 16 + hh) * 64 + d) * 2048 + s] = pk;
            } else {
                float* O = (float*)Cout;
#pragma unroll
                for (int r = 0; r < 4; ++r)
                    O[(long)(row + r) * 1024 + col] = elu(a[r] + bsv);
            }
        }
}

// ---------------- flash attention, 32x32 swapped-QK^T, in-register P --------
// Q: bf16 [B*S][1024] (pre-scaled by 0.125*log2e), Kb: bf16 [B*S][1024],
// Vt: bf16 [B*H*64][2048], mbits: [B*S][32] u64, Co: bf16 [B*S][1024]
__device__ __forceinline__ void attn_tile(
    const u16* Ksb, const u16* Vsb, u64 mw,
    const bf16x8& qf0, const bf16x8& qf1, const bf16x8& qf2, const bf16x8& qf3,
    f32x16& pa0, f32x16& pa1, float& psum, int lo5, int hi2, u32 negbig) {
    const int swz = (lo5 & 7) << 4;
    const int cb  = hi2 * 16;
    const char* Kc = (const char*)Ksb;
    const char* Vc = (const char*)Vsb;

    f32x16 s0 = {}; f32x16 s1 = {};
#define RK(S_, C_) (*(const bf16x8*)(Kc + ((((S_) * 32 + lo5) * 128 + (C_) * 32 + cb) ^ swz)))
    s0 = __builtin_amdgcn_mfma_f32_32x32x16_bf16(RK(0, 0), qf0, s0, 0, 0, 0);
    s1 = __builtin_amdgcn_mfma_f32_32x32x16_bf16(RK(1, 0), qf0, s1, 0, 0, 0);
    s0 = __builtin_amdgcn_mfma_f32_32x32x16_bf16(RK(0, 1), qf1, s0, 0, 0, 0);
    s1 = __builtin_amdgcn_mfma_f32_32x32x16_bf16(RK(1, 1), qf1, s1, 0, 0, 0);
    s0 = __builtin_amdgcn_mfma_f32_32x32x16_bf16(RK(0, 2), qf2, s0, 0, 0, 0);
    s1 = __builtin_amdgcn_mfma_f32_32x32x16_bf16(RK(1, 2), qf2, s1, 0, 0, 0);
    s0 = __builtin_amdgcn_mfma_f32_32x32x16_bf16(RK(0, 3), qf3, s0, 0, 0, 0);
    s1 = __builtin_amdgcn_mfma_f32_32x32x16_bf16(RK(1, 3), qf3, s1, 0, 0, 0);
#undef RK

    // P layout (32x32 C): lane holds P[kv][q=lo5], kv = 32s + (r&3)+8*(r>>2)+4*hi2
#define SUB(SV, SIDX)                                                          \
    {                                                                          \
        u32 wsh = ((u32)(mw >> (SIDX * 32))) >> (hi2 * 4);                     \
        float p[16];                                                           \
        float ls0 = 0.f, ls1 = 0.f;                                            \
        _Pragma("unroll") for (int r = 0; r < 16; ++r) {                       \
            int bit = (r & 3) + 8 * (r >> 2);                                  \
            u32 msk = (u32)((int)(wsh << (31 - bit)) >> 31);                   \
            u32 sb = __float_as_uint(SV[r]);                                   \
            sb = (sb & ~msk) | (negbig & msk);                                 \
            p[r] = __builtin_exp2f(__uint_as_float(sb));                       \
            if (r & 1) ls1 += p[r]; else ls0 += p[r];                          \
        }                                                                      \
        psum += ls0 + ls1;                                                     \
        _Pragma("unroll") for (int th = 0; th < 2; ++th) {                     \
            int rb = th * 8;                                                   \
            u32 a0 = cvtpk(p[rb + 0], p[rb + 1]);                              \
            u32 a1 = cvtpk(p[rb + 2], p[rb + 3]);                              \
            u32 b0 = cvtpk(p[rb + 4], p[rb + 5]);                              \
            u32 b1 = cvtpk(p[rb + 6], p[rb + 7]);                              \
            plswap(a0, b0);                                                    \
            plswap(a1, b1);                                                    \
            u32 au[4] = {a0, a1, b0, b1};                                      \
            bf16x8 pf = *(const bf16x8*)au;                                    \
            int t = SIDX * 2 + th;                                             \
            bf16x8 v0 = *(const bf16x8*)(Vc + ((lo5 * 128 + t * 32 + cb) ^ swz)); \
            pa0 = __builtin_amdgcn_mfma_f32_32x32x16_bf16(pf, v0, pa0, 0, 0, 0);  \
            bf16x8 v1 = *(const bf16x8*)(Vc + (((32 + lo5) * 128 + t * 32 + cb) ^ swz)); \
            pa1 = __builtin_amdgcn_mfma_f32_32x32x16_bf16(pf, v1, pa1, 0, 0, 0);  \
        }                                                                      \
    }
    SUB(s0, 0)
    SUB(s1, 1)
#undef SUB
}

__global__ __launch_bounds__(256, 4) void attn32(const u16* __restrict__ Q,
                                                 const u16* __restrict__ Kb,
                                                 const u16* __restrict__ Vt,
                                                 const u64* __restrict__ mbits,
                                                 u16* __restrict__ Co) {
    const int S = 2048;
    __shared__ u16 Ks[2][64 * 64];   // [kv 64][d 64] bf16, XOR-swizzled 128B rows
    __shared__ u16 Vs[2][64 * 64];   // [d 64][kv 64] bf16, XOR-swizzled

    const int tid = threadIdx.x, lane = tid & 63, w = tid >> 6;
    const int lo5 = lane & 31, hi2 = lane >> 5;
    const int q0 = blockIdx.x * 128;
    const int bh = blockIdx.y, b = bh >> 4, h = bh & 15;
    const u32 negbig = __float_as_uint(-1e30f);

    // Q fragments: B-operand of swapped QK^T. col=q=lo5, k=d=16c+hi2*8+j
    const int qrow = q0 + w * 32 + lo5;
    const u16* qp = Q + (long)(b * S + qrow) * 1024 + h * 64 + hi2 * 8;
    bf16x8 qf0 = *(const bf16x8*)(qp);
    bf16x8 qf1 = *(const bf16x8*)(qp + 16);
    bf16x8 qf2 = *(const bf16x8*)(qp + 32);
    bf16x8 qf3 = *(const bf16x8*)(qp + 48);

    f32x16 pa0 = {}; f32x16 pa1 = {};
    float psum = 0.f;

    const u64* mrow = mbits + (long)(b * S + qrow) * 32;

    // staging: 256 threads x (2 K + 2 V) int4 per 64-kv tile
    const int sr = tid >> 3;             // 0..31
    const int scE = (tid & 7) * 8;       // element offset
    const int wb0 = ((sr * 128 + scE * 2)) ^ ((sr & 7) << 4);
    const int wb1 = (((sr + 32) * 128 + scE * 2)) ^ ((sr & 7) << 4);
    int4 ka0, ka1, va0, va1;

#define LOADKV(KV0)                                                              \
    ka0 = *(const int4*)(Kb + (long)(b * S + (KV0) + sr) * 1024 + h * 64 + scE); \
    ka1 = *(const int4*)(Kb + (long)(b * S + (KV0) + 32 + sr) * 1024 + h * 64 + scE); \
    va0 = *(const int4*)(Vt + ((long)bh * 64 + sr) * 2048 + (KV0) + scE);        \
    va1 = *(const int4*)(Vt + ((long)bh * 64 + 32 + sr) * 2048 + (KV0) + scE);
#define STOREKV(BUF)                                                             \
    *(int4*)((char*)Ks[BUF] + wb0) = ka0;                                        \
    *(int4*)((char*)Ks[BUF] + wb1) = ka1;                                        \
    *(int4*)((char*)Vs[BUF] + wb0) = va0;                                        \
    *(int4*)((char*)Vs[BUF] + wb1) = va1;

    LOADKV(0);
    u64 mw0 = mrow[0], mw1;
    STOREKV(0);
    __syncthreads();

    for (int kvb = 0; kvb < S; kvb += 128) {
        // tile A (buf0 = kvb); prefetch kvb+64 during compute
        LOADKV(kvb + 64);
        mw1 = mrow[(kvb >> 6) + 1];
        attn_tile(Ks[0], Vs[0], mw0, qf0, qf1, qf2, qf3, pa0, pa1, psum, lo5, hi2, negbig);
        STOREKV(1);
        __syncthreads();
        // tile B (buf1 = kvb+64); prefetch kvb+128
        if (kvb + 128 < S) {
            LOADKV(kvb + 128);
            mw0 = mrow[(kvb >> 6) + 2];
        }
        attn_tile(Ks[1], Vs[1], mw1, qf0, qf1, qf2, qf3, pa0, pa1, psum, lo5, hi2, negbig);
        if (kvb + 128 < S) { STOREKV(0); }
        __syncthreads();
    }
#undef LOADKV
#undef STOREKV

    // denominator: lane's psum covers its hi2 half of kv for q-row lo5
    float tot = psum + __shfl_xor(psum, 32);
    float inv = 1.f / tot;

    const long obase = (long)(b * S + q0 + w * 32) * 1024 + h * 64;
#pragma unroll
    for (int r = 0; r < 16; ++r) {
        int ql = (r & 3) + 8 * (r >> 2) + 4 * hi2;
        float iv = __shfl(inv, ql);
        Co[obase + (long)ql * 1024 + lo5]      = f2bf(pa0[r] * iv);
        Co[obase + (long)ql * 1024 + 32 + lo5] = f2bf(pa1[r] * iv);
    }
}

// ---------------- launcher ---------------------------------------------------
extern "C" void kernel_launch(void* const* d_in, const int* in_sizes, int n_in,
                              void* d_out, int out_size, void* d_ws, size_t ws_size,
                              hipStream_t stream) {
    const float* value = (const float*)d_in[0];
    const float* key   = (const float*)d_in[1];
    const float* query = (const float*)d_in[2];
    const int*   mask  = (const int*)d_in[3];
    const float* Wq = (const float*)d_in[4];
    const float* bq = (const float*)d_in[5];
    const float* Wk = (const float*)d_in[6];
    const float* bk = (const float*)d_in[7];
    const float* Wv = (const float*)d_in[8];
    const float* bv = (const float*)d_in[9];
    const float* Wo = (const float*)d_in[10];
    const float* bo = (const float*)d_in[11];

    char* ws = (char*)d_ws;
    const size_t MB2 = 1u << 21, MB16 = 1u << 24;
    u16* Wq_t = (u16*)(ws);
    u16* Wk_t = (u16*)(ws + MB2);
    u16* Wv_t = (u16*)(ws + 2 * MB2);
    u16* Wo_t = (u16*)(ws + 3 * MB2);
    u64* mbits = (u64*)(ws + 4 * MB2);             // 2MB
    u16* Qb  = (u16*)(ws + 5 * MB2);               // 16MB each
    u16* Kb  = (u16*)(ws + 5 * MB2 + MB16);
    u16* Vt  = (u16*)(ws + 5 * MB2 + 2 * MB16);
    u16* Ctx = (u16*)(ws + 5 * MB2 + 3 * MB16);
    u16* Abuf = (u16*)(ws + 5 * MB2 + 4 * MB16);   // reused bf16 A buffer

    dim3 tb(32, 8);
    transpose_w<<<dim3(32, 32), tb, 0, stream>>>(Wq, Wq_t);
    transpose_w<<<dim3(32, 32), tb, 0, stream>>>(Wk, Wk_t);
    transpose_w<<<dim3(32, 32), tb, 0, stream>>>(Wv, Wv_t);
    transpose_w<<<dim3(32, 32), tb, 0, stream>>>(Wo, Wo_t);
    pack_mask<<<1024, 256, 0, stream>>>(mask, mbits, 262144L);

    const int n4 = 8192 * 1024 / 4;
    cvt_bf16<<<2048, 256, 0, stream>>>(query, Abuf, n4);
    gemm_epi<0><<<512, 256, 0, stream>>>(Abuf, Wq_t, bq, Qb);
    cvt_bf16<<<2048, 256, 0, stream>>>(key, Abuf, n4);
    gemm_epi<1><<<512, 256, 0, stream>>>(Abuf, Wk_t, bk, Kb);
    cvt_bf16<<<2048, 256, 0, stream>>>(value, Abuf, n4);
    gemm_epi<2><<<512, 256, 0, stream>>>(Abuf, Wv_t, bv, Vt);

    attn32<<<dim3(16, 64), 256, 0, stream>>>(Qb, Kb, Vt, mbits, Ctx);

    gemm_epi<3><<<512, 256, 0, stream>>>(Ctx, Wo_t, bo, d_out);
}

// Round 4
// 377.388 us; speedup vs baseline: 1.5614x; 1.5614x over previous
//
#include <hip/hip_runtime.h>

typedef unsigned short u16;
typedef unsigned int   u32;
typedef unsigned long long u64;
typedef __bf16 bf16x8 __attribute__((ext_vector_type(8)));
typedef float  f32x4  __attribute__((ext_vector_type(4)));
typedef float  f32x16 __attribute__((ext_vector_type(16)));
typedef u32    u32x4  __attribute__((ext_vector_type(4)));

__device__ __forceinline__ u16 f2bf(float f) {
    u32 u = __float_as_uint(f);
    return (u16)((u + 0x7FFFu + ((u >> 16) & 1u)) >> 16);
}
__device__ __forceinline__ float elu(float x) { return x > 0.f ? x : expm1f(x); }

__device__ __forceinline__ void gload_lds16(const void* g, void* l) {
    __builtin_amdgcn_global_load_lds(
        (const __attribute__((address_space(1))) void*)g,
        (__attribute__((address_space(3))) void*)l, 16, 0, 0);
}

__device__ __forceinline__ u32 cvtpk(float a, float b) {
    u32 r;
    asm("v_cvt_pk_bf16_f32 %0, %1, %2" : "=v"(r) : "v"(a), "v"(b));
    return r;
}
__device__ __forceinline__ void plswap(u32& a, u32& b) {
    asm volatile("v_permlane32_swap_b32 %0, %1" : "+v"(a), "+v"(b));
}

// ---------------- weight transpose + fp32->bf16 : Wt[j][k] = bf16(W[k][j]) ----
__global__ __launch_bounds__(256) void transpose_w(const float* __restrict__ W,
                                                   u16* __restrict__ Wt) {
    __shared__ float t[32][33];
    int j0 = blockIdx.x * 32, k0 = blockIdx.y * 32;
    int tx = threadIdx.x, ty = threadIdx.y; // 32 x 8
#pragma unroll
    for (int i = 0; i < 4; ++i)
        t[ty + i * 8][tx] = W[(long)(k0 + ty + i * 8) * 1024 + j0 + tx];
    __syncthreads();
#pragma unroll
    for (int i = 0; i < 4; ++i)
        Wt[(long)(j0 + ty + i * 8) * 1024 + k0 + tx] = f2bf(t[tx][ty + i * 8]);
}

// ---------------- fp32 -> bf16 bulk convert ---------------------------------
__global__ __launch_bounds__(256) void cvt_bf16(const float* __restrict__ X,
                                                u16* __restrict__ Y, int n4) {
    int i = blockIdx.x * 256 + threadIdx.x;
    int st = gridDim.x * 256;
    for (; i < n4; i += st) {
        float4 v = ((const float4*)X)[i];
        u64 pk = (u64)f2bf(v.x) | ((u64)f2bf(v.y) << 16) |
                 ((u64)f2bf(v.z) << 32) | ((u64)f2bf(v.w) << 48);
        ((u64*)Y)[i] = pk;
    }
}

// ---------------- mask int32 -> bitmask (bit=1 means masked out) -------------
__global__ __launch_bounds__(256) void pack_mask(const int* __restrict__ mask,
                                                 u64* __restrict__ bits, long n64) {
    long wid  = ((long)blockIdx.x * blockDim.x + threadIdx.x) >> 6;
    int  lane = threadIdx.x & 63;
    long nw   = ((long)gridDim.x * blockDim.x) >> 6;
    for (long w = wid; w < n64; w += nw) {
        int m = mask[w * 64 + lane];
        u64 b = __ballot(m != 0);
        if (lane == 0) bits[w] = b;
    }
}

// ---------------- GEMM: C = EPI(elu(A @ Bt^T + bias)), 2-phase dbuf ---------
// A: bf16 [8192][1024], Bt: bf16 [N][K] (pre-transposed)
// EPI: 0=Q (bf16, *0.125*log2e), 1=K (bf16), 2=V -> Vt[b,h,d,s] bf16, 3=out fp32
template <int EPI>
__global__ __launch_bounds__(256) void gemm_epi(const u16* __restrict__ A,
                                                const u16* __restrict__ Bt,
                                                const float* __restrict__ bias,
                                                void* __restrict__ Cout) {
    constexpr int K = 1024;
    __shared__ u16 As[2][128][32];
    __shared__ u16 Bs[2][128][32];
    const int tid = threadIdx.x;
    const int lane = tid & 63, w = tid >> 6;
    const int wm = w >> 1, wn = w & 1;
    // XCD-aware swizzle: 512 blocks = 8 XCDs x 64; each XCD owns one N-panel
    const int vb = ((blockIdx.x & 7) << 6) + (blockIdx.x >> 3);
    const int m0 = (vb & 63) * 128;
    const int n0 = (vb >> 6) * 128;
    const int lrow = lane & 15;
    const int kc = (lane >> 4) * 8;

    const u16* gA = A  + (long)(m0 + w * 16 + (lane >> 2)) * K + (lane & 3) * 8;
    const u16* gB = Bt + (long)(n0 + w * 16 + (lane >> 2)) * K + (lane & 3) * 8;

    f32x4 acc[4][4] = {};

#define STAGE(BUF, KOFF)                                                        \
    gload_lds16(gA + (KOFF), (char*)As[BUF] + w * 1024);                        \
    gload_lds16(gA + 64 * K + (KOFF), (char*)As[BUF] + 4096 + w * 1024);        \
    gload_lds16(gB + (KOFF), (char*)Bs[BUF] + w * 1024);                        \
    gload_lds16(gB + 64 * K + (KOFF), (char*)Bs[BUF] + 4096 + w * 1024);

    STAGE(0, 0);
    __syncthreads();
    int cur = 0;
    for (int k0 = 0; k0 < K; k0 += 32) {
        if (k0 + 32 < K) { STAGE(cur ^ 1, k0 + 32); }
        bf16x8 af[4], bfr[4];
#pragma unroll
        for (int mi = 0; mi < 4; ++mi)
            af[mi] = *(const bf16x8*)&As[cur][wm * 64 + mi * 16 + lrow][kc];
#pragma unroll
        for (int ni = 0; ni < 4; ++ni)
            bfr[ni] = *(const bf16x8*)&Bs[cur][wn * 64 + ni * 16 + lrow][kc];
#pragma unroll
        for (int mi = 0; mi < 4; ++mi)
#pragma unroll
            for (int ni = 0; ni < 4; ++ni)
                acc[mi][ni] = __builtin_amdgcn_mfma_f32_16x16x32_bf16(
                    af[mi], bfr[ni], acc[mi][ni], 0, 0, 0);
        __syncthreads();
        cur ^= 1;
    }
#undef STAGE

    const int rbase = m0 + wm * 64 + (lane >> 4) * 4;
    const int cbase = n0 + wn * 64 + lrow;
#pragma unroll
    for (int mi = 0; mi < 4; ++mi)
#pragma unroll
        for (int ni = 0; ni < 4; ++ni) {
            int row = rbase + mi * 16;
            int col = cbase + ni * 16;
            float bsv = bias[col];
            f32x4 a = acc[mi][ni];
            if (EPI == 0 || EPI == 1) {
                u16* O = (u16*)Cout;
#pragma unroll
                for (int r = 0; r < 4; ++r) {
                    float v = elu(a[r] + bsv);
                    if (EPI == 0) v *= 0.18033688011112042f; // (1/8)*log2(e)
                    O[(long)(row + r) * 1024 + col] = f2bf(v);
                }
            } else if (EPI == 2) {
                u16* O = (u16*)Cout;
                int bb = row >> 11, s = row & 2047;
                int hh = col >> 6, d = col & 63;
                u64 pk = (u64)f2bf(elu(a[0] + bsv)) |
                         ((u64)f2bf(elu(a[1] + bsv)) << 16) |
                         ((u64)f2bf(elu(a[2] + bsv)) << 32) |
                         ((u64)f2bf(elu(a[3] + bsv)) << 48);
                *(u64*)&O[((long)(bb * 16 + hh) * 64 + d) * 2048 + s] = pk;
            } else {
                float* O = (float*)Cout;
#pragma unroll
                for (int r = 0; r < 4; ++r)
                    O[(long)(row + r) * 1024 + col] = elu(a[r] + bsv);
            }
        }
}

// ---------------- flash attention, 32x32 swapped-QK^T, in-register P --------
// Q: bf16 [B*S][1024] (pre-scaled by 0.125*log2e), Kb: bf16 [B*S][1024],
// Vt: bf16 [B*H*64][2048], mbits: [B*S][32] u64, Co: bf16 [B*S][1024]
__device__ __forceinline__ void attn_tile(
    const u16* Ksb, const u16* Vsb, u64 mw,
    const bf16x8& qf0, const bf16x8& qf1, const bf16x8& qf2, const bf16x8& qf3,
    f32x16& pa0, f32x16& pa1, float& psum, int lo5, int hi2) {
    const int swz = (lo5 & 7) << 4;
    const int cb  = hi2 * 16;
    const char* Kc = (const char*)Ksb;
    const char* Vc = (const char*)Vsb;
#pragma unroll
    for (int sidx = 0; sidx < 2; ++sidx) {
        // one 32x32 score subtile at a time (halves live registers)
        f32x16 s = {};
#define RK(C_) (*(const bf16x8*)(Kc + (((sidx * 32 + lo5) * 128 + (C_) * 32 + cb) ^ swz)))
        s = __builtin_amdgcn_mfma_f32_32x32x16_bf16(RK(0), qf0, s, 0, 0, 0);
        s = __builtin_amdgcn_mfma_f32_32x32x16_bf16(RK(1), qf1, s, 0, 0, 0);
        s = __builtin_amdgcn_mfma_f32_32x32x16_bf16(RK(2), qf2, s, 0, 0, 0);
        s = __builtin_amdgcn_mfma_f32_32x32x16_bf16(RK(3), qf3, s, 0, 0, 0);
#undef RK
        // keep-mask: bit=1 means masked; zero p after exp (exact zeros)
        u32 nw = ~(((u32)(mw >> (sidx * 32))) >> (hi2 * 4));
        float p[16];
        float ls0 = 0.f, ls1 = 0.f;
#pragma unroll
        for (int r = 0; r < 16; ++r) {
            int bit = (r & 3) + 8 * (r >> 2);
            u32 keep = (u32)((int)(nw << (31 - bit)) >> 31);
            float pe = __builtin_exp2f(s[r]);
            p[r] = __uint_as_float(__float_as_uint(pe) & keep);
            if (r & 1) ls1 += p[r]; else ls0 += p[r];
        }
        psum += ls0 + ls1;
#pragma unroll
        for (int th = 0; th < 2; ++th) {
            int rb = th * 8;
            u32 a0 = cvtpk(p[rb + 0], p[rb + 1]);
            u32 a1 = cvtpk(p[rb + 2], p[rb + 3]);
            u32 b0 = cvtpk(p[rb + 4], p[rb + 5]);
            u32 b1 = cvtpk(p[rb + 6], p[rb + 7]);
            plswap(a0, b0);
            plswap(a1, b1);
            u32x4 au; au.x = a0; au.y = a1; au.z = b0; au.w = b1;
            bf16x8 pf = __builtin_bit_cast(bf16x8, au);  // registers, no scratch
            int t = sidx * 2 + th;
            bf16x8 v0 = *(const bf16x8*)(Vc + ((lo5 * 128 + t * 32 + cb) ^ swz));
            pa0 = __builtin_amdgcn_mfma_f32_32x32x16_bf16(pf, v0, pa0, 0, 0, 0);
            bf16x8 v1 = *(const bf16x8*)(Vc + (((32 + lo5) * 128 + t * 32 + cb) ^ swz));
            pa1 = __builtin_amdgcn_mfma_f32_32x32x16_bf16(pf, v1, pa1, 0, 0, 0);
        }
    }
}

__global__ __launch_bounds__(256) void attn32(const u16* __restrict__ Q,
                                              const u16* __restrict__ Kb,
                                              const u16* __restrict__ Vt,
                                              const u64* __restrict__ mbits,
                                              u16* __restrict__ Co) {
    const int S = 2048;
    __shared__ u16 Ks[2][64 * 64];   // [kv 64][d 64], rows 128B, XOR-swizzled content
    __shared__ u16 Vs[2][64 * 64];   // [d 64][kv 64], XOR-swizzled content

    const int tid = threadIdx.x, lane = tid & 63, w = tid >> 6;
    const int lo5 = lane & 31, hi2 = lane >> 5;
    const int q0 = blockIdx.x * 128;
    const int bh = blockIdx.y, b = bh >> 4, h = bh & 15;

    // Q fragments: B-operand of swapped QK^T. col=q=lo5, k=d
    const int qrow = q0 + w * 32 + lo5;
    const u16* qp = Q + (long)(b * S + qrow) * 1024 + h * 64 + hi2 * 8;
    bf16x8 qf0 = *(const bf16x8*)(qp);
    bf16x8 qf1 = *(const bf16x8*)(qp + 16);
    bf16x8 qf2 = *(const bf16x8*)(qp + 32);
    bf16x8 qf3 = *(const bf16x8*)(qp + 48);

    f32x16 pa0 = {}; f32x16 pa1 = {};
    float psum = 0.f;

    const u64* mrow = mbits + (long)(b * S + qrow) * 32;

    // gload_lds staging: linear LDS dest (wave base + lane*16), pre-swizzled
    // global source so READ-side XOR swizzle sees the right bytes (involution).
    const int r_  = w * 16 + (lane >> 3);           // LDS row for this lane
    const int cp_ = (lane & 7) ^ ((lane >> 3) & 7); // pre-swizzled 16B chunk
    const u16* kSrc = Kb + (long)(b * S + r_) * 1024 + h * 64 + cp_ * 8;
    const u16* vSrc = Vt + ((long)bh * 64 + r_) * 2048 + cp_ * 8;

#define STAGE(BUF, T)                                                          \
    gload_lds16(kSrc + (long)(T) * 65536,            (char*)Ks[BUF] + w * 2048);        \
    gload_lds16(kSrc + (long)(T) * 65536 + 8192,     (char*)Ks[BUF] + w * 2048 + 1024); \
    gload_lds16(vSrc + (long)(T) * 64,               (char*)Vs[BUF] + w * 2048);        \
    gload_lds16(vSrc + (long)(T) * 64 + 8 * 2048,    (char*)Vs[BUF] + w * 2048 + 1024);

    int buf = 0;
    u64 mw = mrow[0], mwn = 0;
    STAGE(0, 0);
    __syncthreads();

    for (int t = 0; t < 32; ++t) {
        if (t < 31) { STAGE(buf ^ 1, t + 1); mwn = mrow[t + 1]; }
        attn_tile(Ks[buf], Vs[buf], mw, qf0, qf1, qf2, qf3, pa0, pa1, psum, lo5, hi2);
        __syncthreads();
        mw = mwn; buf ^= 1;
    }
#undef STAGE

    // denominator: lane covers its hi2 half of kv for q-row lo5
    float tot = psum + __shfl_xor(psum, 32);
    float inv = 1.f / tot;

    const long obase = (long)(b * S + q0 + w * 32) * 1024 + h * 64;
#pragma unroll
    for (int r = 0; r < 16; ++r) {
        int ql = (r & 3) + 8 * (r >> 2) + 4 * hi2;
        float iv = __shfl(inv, ql);
        Co[obase + (long)ql * 1024 + lo5]      = f2bf(pa0[r] * iv);
        Co[obase + (long)ql * 1024 + 32 + lo5] = f2bf(pa1[r] * iv);
    }
}

// ---------------- launcher ---------------------------------------------------
extern "C" void kernel_launch(void* const* d_in, const int* in_sizes, int n_in,
                              void* d_out, int out_size, void* d_ws, size_t ws_size,
                              hipStream_t stream) {
    const float* value = (const float*)d_in[0];
    const float* key   = (const float*)d_in[1];
    const float* query = (const float*)d_in[2];
    const int*   mask  = (const int*)d_in[3];
    const float* Wq = (const float*)d_in[4];
    const float* bq = (const float*)d_in[5];
    const float* Wk = (const float*)d_in[6];
    const float* bk = (const float*)d_in[7];
    const float* Wv = (const float*)d_in[8];
    const float* bv = (const float*)d_in[9];
    const float* Wo = (const float*)d_in[10];
    const float* bo = (const float*)d_in[11];

    char* ws = (char*)d_ws;
    const size_t MB2 = 1u << 21, MB16 = 1u << 24;
    u16* Wq_t = (u16*)(ws);
    u16* Wk_t = (u16*)(ws + MB2);
    u16* Wv_t = (u16*)(ws + 2 * MB2);
    u16* Wo_t = (u16*)(ws + 3 * MB2);
    u64* mbits = (u64*)(ws + 4 * MB2);             // 2MB
    u16* Qb  = (u16*)(ws + 5 * MB2);               // 16MB each
    u16* Kb  = (u16*)(ws + 5 * MB2 + MB16);
    u16* Vt  = (u16*)(ws + 5 * MB2 + 2 * MB16);
    u16* Ctx = (u16*)(ws + 5 * MB2 + 3 * MB16);
    u16* Abuf = (u16*)(ws + 5 * MB2 + 4 * MB16);   // reused bf16 A buffer

    dim3 tb(32, 8);
    transpose_w<<<dim3(32, 32), tb, 0, stream>>>(Wq, Wq_t);
    transpose_w<<<dim3(32, 32), tb, 0, stream>>>(Wk, Wk_t);
    transpose_w<<<dim3(32, 32), tb, 0, stream>>>(Wv, Wv_t);
    transpose_w<<<dim3(32, 32), tb, 0, stream>>>(Wo, Wo_t);
    pack_mask<<<1024, 256, 0, stream>>>(mask, mbits, 262144L);

    const int n4 = 8192 * 1024 / 4;
    cvt_bf16<<<2048, 256, 0, stream>>>(query, Abuf, n4);
    gemm_epi<0><<<512, 256, 0, stream>>>(Abuf, Wq_t, bq, Qb);
    cvt_bf16<<<2048, 256, 0, stream>>>(key, Abuf, n4);
    gemm_epi<1><<<512, 256, 0, stream>>>(Abuf, Wk_t, bk, Kb);
    cvt_bf16<<<2048, 256, 0, stream>>>(value, Abuf, n4);
    gemm_epi<2><<<512, 256, 0, stream>>>(Abuf, Wv_t, bv, Vt);

    attn32<<<dim3(16, 64), 256, 0, stream>>>(Qb, Kb, Vt, mbits, Ctx);

    gemm_epi<3><<<512, 256, 0, stream>>>(Ctx, Wo_t, bo, d_out);
}

// Round 5
// 294.282 us; speedup vs baseline: 2.0024x; 1.2824x over previous
//
#include <hip/hip_runtime.h>

typedef unsigned short u16;
typedef unsigned int   u32;
typedef unsigned long long u64;
typedef __bf16 bf16x8 __attribute__((ext_vector_type(8)));
typedef float  f32x4  __attribute__((ext_vector_type(4)));
typedef float  f32x16 __attribute__((ext_vector_type(16)));
typedef u32    u32x4  __attribute__((ext_vector_type(4)));

__device__ __forceinline__ u16 f2bf(float f) {
    u32 u = __float_as_uint(f);
    return (u16)((u + 0x7FFFu + ((u >> 16) & 1u)) >> 16);
}
// raw HW exp2 (no denormal-handling expansion)
__device__ __forceinline__ float fexp2(float x) {
    float r;
    asm("v_exp_f32 %0, %1" : "=v"(r) : "v"(x));
    return r;
}
__device__ __forceinline__ float elu_f(float x) {
    return x > 0.f ? x : fexp2(x * 1.44269504088896341f) - 1.f;
}
__device__ __forceinline__ void gload_lds16(const void* g, void* l) {
    __builtin_amdgcn_global_load_lds(
        (const __attribute__((address_space(1))) void*)g,
        (__attribute__((address_space(3))) void*)l, 16, 0, 0);
}
__device__ __forceinline__ u32 cvtpk(float a, float b) {
    u32 r;
    asm("v_cvt_pk_bf16_f32 %0, %1, %2" : "=v"(r) : "v"(a), "v"(b));
    return r;
}
__device__ __forceinline__ void plswap(u32& a, u32& b) {
    asm volatile("v_permlane32_swap_b32 %0, %1" : "+v"(a), "+v"(b));
}

// ---------------- 4x weight transpose + fp32->bf16 --------------------------
__global__ __launch_bounds__(256) void transpose_w4(
    const float* __restrict__ W0, const float* __restrict__ W1,
    const float* __restrict__ W2, const float* __restrict__ W3,
    u16* __restrict__ T0, u16* __restrict__ T1,
    u16* __restrict__ T2, u16* __restrict__ T3) {
    const float* W = blockIdx.z == 0 ? W0 : blockIdx.z == 1 ? W1 : blockIdx.z == 2 ? W2 : W3;
    u16* Wt        = blockIdx.z == 0 ? T0 : blockIdx.z == 1 ? T1 : blockIdx.z == 2 ? T2 : T3;
    __shared__ float t[32][33];
    int j0 = blockIdx.x * 32, k0 = blockIdx.y * 32;
    int tx = threadIdx.x, ty = threadIdx.y; // 32 x 8
#pragma unroll
    for (int i = 0; i < 4; ++i)
        t[ty + i * 8][tx] = W[(long)(k0 + ty + i * 8) * 1024 + j0 + tx];
    __syncthreads();
#pragma unroll
    for (int i = 0; i < 4; ++i)
        Wt[(long)(j0 + ty + i * 8) * 1024 + k0 + tx] = f2bf(t[tx][ty + i * 8]);
}

// ---------------- fp32 -> bf16 bulk convert ---------------------------------
__global__ __launch_bounds__(256) void cvt_bf16(const float* __restrict__ X,
                                                u16* __restrict__ Y, int n4) {
    int i = blockIdx.x * 256 + threadIdx.x;
    int st = gridDim.x * 256;
    for (; i < n4; i += st) {
        float4 v = ((const float4*)X)[i];
        u64 pk = (u64)f2bf(v.x) | ((u64)f2bf(v.y) << 16) |
                 ((u64)f2bf(v.z) << 32) | ((u64)f2bf(v.w) << 48);
        ((u64*)Y)[i] = pk;
    }
}

// ---------------- mask int32 -> bitmask (bit=1 means masked out) -------------
__global__ __launch_bounds__(256) void pack_mask(const int* __restrict__ mask,
                                                 u64* __restrict__ bits, long n64) {
    long wid  = ((long)blockIdx.x * blockDim.x + threadIdx.x) >> 6;
    int  lane = threadIdx.x & 63;
    long nw   = ((long)gridDim.x * blockDim.x) >> 6;
    for (long w = wid; w < n64; w += nw) {
        int m = mask[w * 64 + lane];
        u64 b = __ballot(m != 0);
        if (lane == 0) bits[w] = b;
    }
}

// ---------------- GEMM body: BK=64, 2-phase dbuf, swizzled LDS --------------
// Computes acc[4][4] for 128x128 tile of A @ Bt^T. Shared by qkv + out kernels.
#define GEMM_BODY(A_, Bt_)                                                      \
    const int tid = threadIdx.x, lane = tid & 63, w = tid >> 6;                 \
    const int wm = w >> 1, wn = w & 1;                                          \
    const int vb = ((blockIdx.x & 7) << 6) + (blockIdx.x >> 3);                 \
    const int m0 = (vb & 63) * 128;                                             \
    const int n0 = (vb >> 6) * 128;                                             \
    const int lrow = lane & 15;                                                 \
    const int hi4 = lane >> 4;                                                  \
    const int srow = w * 32 + (lane >> 3);                                      \
    const int scw = ((lane & 7) ^ ((lane >> 3) & 7)) * 8;                       \
    const u16* gA = (A_) + (long)(m0 + srow) * 1024 + scw;                      \
    const u16* gB = (Bt_) + (long)(n0 + srow) * 1024 + scw;                     \
    f32x4 acc[4][4] = {};                                                       \
    STAGE(0, 0);                                                                \
    __syncthreads();                                                            \
    int cur = 0;                                                                \
    const int rswz = (lrow & 7) << 4;                                           \
    for (int k0 = 0; k0 < 1024; k0 += 64) {                                     \
        if (k0 + 64 < 1024) { STAGE(cur ^ 1, k0 + 64); }                        \
        const char* Ac = (const char*)As[cur];                                  \
        const char* Bc = (const char*)Bs[cur];                                  \
        _Pragma("unroll") for (int kk = 0; kk < 2; ++kk) {                      \
            bf16x8 af[4], bfr[4];                                               \
            _Pragma("unroll") for (int mi = 0; mi < 4; ++mi) {                  \
                int r = wm * 64 + mi * 16 + lrow;                               \
                af[mi] = *(const bf16x8*)(Ac + ((r * 128 + kk * 64 + hi4 * 16) ^ rswz)); \
            }                                                                   \
            _Pragma("unroll") for (int ni = 0; ni < 4; ++ni) {                  \
                int r = wn * 64 + ni * 16 + lrow;                               \
                bfr[ni] = *(const bf16x8*)(Bc + ((r * 128 + kk * 64 + hi4 * 16) ^ rswz)); \
            }                                                                   \
            _Pragma("unroll") for (int mi = 0; mi < 4; ++mi)                    \
                _Pragma("unroll") for (int ni = 0; ni < 4; ++ni)                \
                    acc[mi][ni] = __builtin_amdgcn_mfma_f32_16x16x32_bf16(      \
                        af[mi], bfr[ni], acc[mi][ni], 0, 0, 0);                 \
        }                                                                       \
        __syncthreads();                                                        \
        cur ^= 1;                                                               \
    }

#define STAGE(BUF, KOFF)                                                        \
    gload_lds16(gA + (KOFF),            (char*)As[BUF] + w * 4096);             \
    gload_lds16(gA + 8 * 1024 + (KOFF), (char*)As[BUF] + w * 4096 + 1024);      \
    gload_lds16(gA + 16 * 1024 + (KOFF), (char*)As[BUF] + w * 4096 + 2048);     \
    gload_lds16(gA + 24 * 1024 + (KOFF), (char*)As[BUF] + w * 4096 + 3072);     \
    gload_lds16(gB + (KOFF),            (char*)Bs[BUF] + w * 4096);             \
    gload_lds16(gB + 8 * 1024 + (KOFF), (char*)Bs[BUF] + w * 4096 + 1024);      \
    gload_lds16(gB + 16 * 1024 + (KOFF), (char*)Bs[BUF] + w * 4096 + 2048);     \
    gload_lds16(gB + 24 * 1024 + (KOFF), (char*)Bs[BUF] + w * 4096 + 3072);

// ---------------- merged Q/K/V projection GEMM ------------------------------
// z=0: Q (bf16, *0.125*log2e) -> Qb[b*s][1024]
// z=1: K (bf16)               -> Kb[b*s][1024]
// z=2: V -> Vt[b,h,d,s] bf16 via LDS transpose (coalesced writes)
__global__ __launch_bounds__(256) void gemm_qkv(
    const u16* __restrict__ Aq, const u16* __restrict__ Ak, const u16* __restrict__ Av,
    const u16* __restrict__ Wqt, const u16* __restrict__ Wkt, const u16* __restrict__ Wvt,
    const float* __restrict__ bq, const float* __restrict__ bk, const float* __restrict__ bv,
    u16* __restrict__ Qb, u16* __restrict__ Kb, u16* __restrict__ Vt, int zforce) {
    __shared__ u16 As[2][128 * 64];
    __shared__ u16 Bs[2][128 * 64];
    const int z = zforce >= 0 ? zforce : blockIdx.y;
    const u16* A     = z == 0 ? Aq : z == 1 ? Ak : Av;
    const u16* Bt    = z == 0 ? Wqt : z == 1 ? Wkt : Wvt;
    const float* bias = z == 0 ? bq : z == 1 ? bk : bv;

    GEMM_BODY(A, Bt)

    if (z != 2) {
        u16* O = z == 0 ? Qb : Kb;
        const int rbase = m0 + wm * 64 + hi4 * 4;
        const int cbase = n0 + wn * 64 + lrow;
#pragma unroll
        for (int mi = 0; mi < 4; ++mi)
#pragma unroll
            for (int ni = 0; ni < 4; ++ni) {
                int row = rbase + mi * 16;
                int col = cbase + ni * 16;
                float bsv = bias[col];
                f32x4 a = acc[mi][ni];
#pragma unroll
                for (int r = 0; r < 4; ++r) {
                    float v = elu_f(a[r] + bsv);
                    if (z == 0) v *= 0.18033688011112042f; // (1/8)*log2(e)
                    O[(long)(row + r) * 1024 + col] = f2bf(v);
                }
            }
    } else {
        // transpose via LDS: tile [128 d][32 sblk] of u64 (4 s-contig bf16)
        __syncthreads();
        char* T = (char*)&As[0][0];
#pragma unroll
        for (int mi = 0; mi < 4; ++mi)
#pragma unroll
            for (int ni = 0; ni < 4; ++ni) {
                int d = wn * 64 + ni * 16 + lrow;
                int sb = wm * 16 + mi * 4 + hi4;
                float bsv = bias[n0 + d];
                f32x4 a = acc[mi][ni];
                u64 pk = (u64)f2bf(elu_f(a[0] + bsv)) |
                         ((u64)f2bf(elu_f(a[1] + bsv)) << 16) |
                         ((u64)f2bf(elu_f(a[2] + bsv)) << 32) |
                         ((u64)f2bf(elu_f(a[3] + bsv)) << 48);
                *(u64*)(T + ((d * 256 + sb * 8) ^ ((d & 15) << 3))) = pk;
            }
        __syncthreads();
        const int bb = m0 >> 11, sbase = m0 & 2047;
        const int d = tid >> 1;
        const int s0 = (tid & 1) * 16;  // u64 index within 32
        const int dm = n0 + d;
        long gb = ((long)(bb * 16 + (dm >> 6)) * 64 + (dm & 63)) * 2048 + sbase;
#pragma unroll
        for (int c = 0; c < 8; ++c) {
            int si = s0 + 2 * c;
            u64 lo = *(u64*)(T + ((d * 256 + si * 8) ^ ((d & 15) << 3)));
            u64 hi = *(u64*)(T + ((d * 256 + (si + 1) * 8) ^ ((d & 15) << 3)));
            *(u64*)(Vt + gb + si * 4) = lo;
            *(u64*)(Vt + gb + si * 4 + 4) = hi;
        }
    }
}

// ---------------- output GEMM: elu(Ctx @ Wo^T + bo) -> fp32 -----------------
__global__ __launch_bounds__(256) void gemm_out(const u16* __restrict__ Actx,
                                                const u16* __restrict__ Wot,
                                                const float* __restrict__ bias,
                                                float* __restrict__ Out) {
    __shared__ u16 As[2][128 * 64];
    __shared__ u16 Bs[2][128 * 64];

    GEMM_BODY(Actx, Wot)

    const int rbase = m0 + wm * 64 + hi4 * 4;
    const int cbase = n0 + wn * 64 + lrow;
#pragma unroll
    for (int mi = 0; mi < 4; ++mi)
#pragma unroll
        for (int ni = 0; ni < 4; ++ni) {
            int row = rbase + mi * 16;
            int col = cbase + ni * 16;
            float bsv = bias[col];
            f32x4 a = acc[mi][ni];
#pragma unroll
            for (int r = 0; r < 4; ++r)
                Out[(long)(row + r) * 1024 + col] = elu_f(a[r] + bsv);
        }
}

// ---------------- flash attention, 32x32 swapped-QK^T, in-register P --------
__device__ __forceinline__ void attn_tile(
    const u16* Ksb, const u16* Vsb, u64 mw,
    const bf16x8& qf0, const bf16x8& qf1, const bf16x8& qf2, const bf16x8& qf3,
    f32x16& pa0, f32x16& pa1, float& psum, int lo5, int hi2) {
    const int swz = (lo5 & 7) << 4;
    const int cb  = hi2 * 16;
    const char* Kc = (const char*)Ksb;
    const char* Vc = (const char*)Vsb;
#pragma unroll
    for (int sidx = 0; sidx < 2; ++sidx) {
        f32x16 s = {};
#define RK(C_) (*(const bf16x8*)(Kc + (((sidx * 32 + lo5) * 128 + (C_) * 32 + cb) ^ swz)))
        s = __builtin_amdgcn_mfma_f32_32x32x16_bf16(RK(0), qf0, s, 0, 0, 0);
        s = __builtin_amdgcn_mfma_f32_32x32x16_bf16(RK(1), qf1, s, 0, 0, 0);
        s = __builtin_amdgcn_mfma_f32_32x32x16_bf16(RK(2), qf2, s, 0, 0, 0);
        s = __builtin_amdgcn_mfma_f32_32x32x16_bf16(RK(3), qf3, s, 0, 0, 0);
#undef RK
        u32 nw = ~(((u32)(mw >> (sidx * 32))) >> (hi2 * 4));
        float p[16];
        float ls0 = 0.f, ls1 = 0.f;
#pragma unroll
        for (int r = 0; r < 16; ++r) {
            int bit = (r & 3) + 8 * (r >> 2);
            u32 keep = (u32)((int)(nw << (31 - bit)) >> 31);
            float pe = fexp2(s[r]);  // raw v_exp_f32
            p[r] = __uint_as_float(__float_as_uint(pe) & keep);
            if (r & 1) ls1 += p[r]; else ls0 += p[r];
        }
        psum += ls0 + ls1;
#pragma unroll
        for (int th = 0; th < 2; ++th) {
            int rb = th * 8;
            u32 a0 = cvtpk(p[rb + 0], p[rb + 1]);
            u32 a1 = cvtpk(p[rb + 2], p[rb + 3]);
            u32 b0 = cvtpk(p[rb + 4], p[rb + 5]);
            u32 b1 = cvtpk(p[rb + 6], p[rb + 7]);
            plswap(a0, b0);
            plswap(a1, b1);
            u32x4 au; au.x = a0; au.y = a1; au.z = b0; au.w = b1;
            bf16x8 pf = __builtin_bit_cast(bf16x8, au);
            int t = sidx * 2 + th;
            bf16x8 v0 = *(const bf16x8*)(Vc + ((lo5 * 128 + t * 32 + cb) ^ swz));
            pa0 = __builtin_amdgcn_mfma_f32_32x32x16_bf16(pf, v0, pa0, 0, 0, 0);
            bf16x8 v1 = *(const bf16x8*)(Vc + (((32 + lo5) * 128 + t * 32 + cb) ^ swz));
            pa1 = __builtin_amdgcn_mfma_f32_32x32x16_bf16(pf, v1, pa1, 0, 0, 0);
        }
    }
}

__global__ __launch_bounds__(256, 3) void attn32(const u16* __restrict__ Q,
                                                 const u16* __restrict__ Kb,
                                                 const u16* __restrict__ Vt,
                                                 const u64* __restrict__ mbits,
                                                 u16* __restrict__ Co) {
    const int S = 2048;
    __shared__ u16 Ks[2][64 * 64];
    __shared__ u16 Vs[2][64 * 64];

    const int tid = threadIdx.x, lane = tid & 63, w = tid >> 6;
    const int lo5 = lane & 31, hi2 = lane >> 5;
    const int q0 = blockIdx.x * 128;
    const int bh = blockIdx.y, b = bh >> 4, h = bh & 15;

    const int qrow = q0 + w * 32 + lo5;
    const u16* qp = Q + (long)(b * S + qrow) * 1024 + h * 64 + hi2 * 8;
    bf16x8 qf0 = *(const bf16x8*)(qp);
    bf16x8 qf1 = *(const bf16x8*)(qp + 16);
    bf16x8 qf2 = *(const bf16x8*)(qp + 32);
    bf16x8 qf3 = *(const bf16x8*)(qp + 48);

    f32x16 pa0 = {}; f32x16 pa1 = {};
    float psum = 0.f;

    const u64* mrow = mbits + (long)(b * S + qrow) * 32;

    const int r_  = w * 16 + (lane >> 3);
    const int cp_ = (lane & 7) ^ ((lane >> 3) & 7);
    const u16* kSrc = Kb + (long)(b * S + r_) * 1024 + h * 64 + cp_ * 8;
    const u16* vSrc = Vt + ((long)bh * 64 + r_) * 2048 + cp_ * 8;

#define STAGEA(BUF, T)                                                         \
    gload_lds16(kSrc + (long)(T) * 65536,         (char*)Ks[BUF] + w * 2048);        \
    gload_lds16(kSrc + (long)(T) * 65536 + 8192,  (char*)Ks[BUF] + w * 2048 + 1024); \
    gload_lds16(vSrc + (long)(T) * 64,            (char*)Vs[BUF] + w * 2048);        \
    gload_lds16(vSrc + (long)(T) * 64 + 8 * 2048, (char*)Vs[BUF] + w * 2048 + 1024);

    int buf = 0;
    u64 mw = mrow[0], mwn = 0;
    STAGEA(0, 0);
    __syncthreads();

    for (int t = 0; t < 32; ++t) {
        if (t < 31) { STAGEA(buf ^ 1, t + 1); mwn = mrow[t + 1]; }
        attn_tile(Ks[buf], Vs[buf], mw, qf0, qf1, qf2, qf3, pa0, pa1, psum, lo5, hi2);
        __syncthreads();
        mw = mwn; buf ^= 1;
    }
#undef STAGEA

    float tot = psum + __shfl_xor(psum, 32);
    float inv = 1.f / tot;

    const long obase = (long)(b * S + q0 + w * 32) * 1024 + h * 64;
#pragma unroll
    for (int r = 0; r < 16; ++r) {
        int ql = (r & 3) + 8 * (r >> 2) + 4 * hi2;
        float iv = __shfl(inv, ql);
        Co[obase + (long)ql * 1024 + lo5]      = f2bf(pa0[r] * iv);
        Co[obase + (long)ql * 1024 + 32 + lo5] = f2bf(pa1[r] * iv);
    }
}

// ---------------- launcher ---------------------------------------------------
extern "C" void kernel_launch(void* const* d_in, const int* in_sizes, int n_in,
                              void* d_out, int out_size, void* d_ws, size_t ws_size,
                              hipStream_t stream) {
    const float* value = (const float*)d_in[0];
    const float* key   = (const float*)d_in[1];
    const float* query = (const float*)d_in[2];
    const int*   mask  = (const int*)d_in[3];
    const float* Wq = (const float*)d_in[4];
    const float* bq = (const float*)d_in[5];
    const float* Wk = (const float*)d_in[6];
    const float* bk = (const float*)d_in[7];
    const float* Wv = (const float*)d_in[8];
    const float* bv = (const float*)d_in[9];
    const float* Wo = (const float*)d_in[10];
    const float* bo = (const float*)d_in[11];

    char* ws = (char*)d_ws;
    const size_t MB2 = 1u << 21, MB16 = 1u << 24;
    u16* Wq_t = (u16*)(ws);
    u16* Wk_t = (u16*)(ws + MB2);
    u16* Wv_t = (u16*)(ws + 2 * MB2);
    u16* Wo_t = (u16*)(ws + 3 * MB2);
    u64* mbits = (u64*)(ws + 4 * MB2);
    char* big0 = ws + 5 * MB2;
    u16* Qb = (u16*)(big0);
    u16* Kb = (u16*)(big0 + MB16);
    u16* Vt = (u16*)(big0 + 2 * MB16);
    u16* Aq = (u16*)(big0 + 3 * MB16);  // also Ctx (reused after Q-GEMM reads it)
    u16* Ctx = Aq;
    u16* Ak = (u16*)(big0 + 4 * MB16);
    u16* Av = (u16*)(big0 + 5 * MB16);
    const bool bigws = ws_size >= (size_t)(5 * MB2 + 6 * MB16);

    transpose_w4<<<dim3(32, 32, 4), dim3(32, 8), 0, stream>>>(
        Wq, Wk, Wv, Wo, Wq_t, Wk_t, Wv_t, Wo_t);
    pack_mask<<<1024, 256, 0, stream>>>(mask, mbits, 262144L);

    const int n4 = 8192 * 1024 / 4;
    if (bigws) {
        cvt_bf16<<<2048, 256, 0, stream>>>(query, Aq, n4);
        cvt_bf16<<<2048, 256, 0, stream>>>(key,   Ak, n4);
        cvt_bf16<<<2048, 256, 0, stream>>>(value, Av, n4);
        gemm_qkv<<<dim3(512, 3), 256, 0, stream>>>(Aq, Ak, Av, Wq_t, Wk_t, Wv_t,
                                                   bq, bk, bv, Qb, Kb, Vt, -1);
    } else {
        cvt_bf16<<<2048, 256, 0, stream>>>(query, Aq, n4);
        gemm_qkv<<<dim3(512, 1), 256, 0, stream>>>(Aq, Aq, Aq, Wq_t, Wk_t, Wv_t,
                                                   bq, bk, bv, Qb, Kb, Vt, 0);
        cvt_bf16<<<2048, 256, 0, stream>>>(key, Aq, n4);
        gemm_qkv<<<dim3(512, 1), 256, 0, stream>>>(Aq, Aq, Aq, Wq_t, Wk_t, Wv_t,
                                                   bq, bk, bv, Qb, Kb, Vt, 1);
        cvt_bf16<<<2048, 256, 0, stream>>>(value, Aq, n4);
        gemm_qkv<<<dim3(512, 1), 256, 0, stream>>>(Aq, Aq, Aq, Wq_t, Wk_t, Wv_t,
                                                   bq, bk, bv, Qb, Kb, Vt, 2);
    }

    attn32<<<dim3(16, 64), 256, 0, stream>>>(Qb, Kb, Vt, mbits, Ctx);
    gemm_out<<<512, 256, 0, stream>>>(Ctx, Wo_t, bo, (float*)d_out);
}